// Round 1
// baseline (155.088 us; speedup 1.0000x reference)
//
#include <hip/hip_runtime.h>
#include <cstdint>

#define PI_F 3.14159265358979323846f

__device__ __forceinline__ float fract_(float x)  { return __builtin_amdgcn_fractf(x); }
__device__ __forceinline__ float sin2pi_(float r) { return __builtin_amdgcn_sinf(r); }  // sin(2*pi*r)
__device__ __forceinline__ float cos2pi_(float r) { return __builtin_amdgcn_cosf(r); }  // cos(2*pi*r)

// ---------------------------------------------------------------------------
// Kernel A: compress z_real/z_imag (values +-1) to sign bitmasks.
// bit (k&63) of word pair [item*8 + k/32] is set iff z[item][k] < 0.
// Fully coalesced 67 MB read, 2.1 MB write.
// ---------------------------------------------------------------------------
extern "C" __global__ void pack_signs(const float* __restrict__ zr,
                                      const float* __restrict__ zi,
                                      uint32_t* __restrict__ pr,
                                      uint32_t* __restrict__ pim) {
    const int t = blockIdx.x * 256 + threadIdx.x;
    const float a = zr[t];
    const float b = zi[t];
    unsigned long long br = __ballot(a < 0.0f);
    unsigned long long bi = __ballot(b < 0.0f);
    if ((threadIdx.x & 31) == 0) {
        const int sh = threadIdx.x & 32;         // lane 0 -> low 32 bits, lane 32 -> high
        pr [t >> 5] = (uint32_t)(br >> sh);
        pim[t >> 5] = (uint32_t)(bi >> sh);
    }
}

// ---------------------------------------------------------------------------
// Kernel B: the refiner. lane = item; 4 waves per block split K=256 into
// 64 k's per lane. Per k (fully unrolled): rotation-chain phase update,
// sign-bit XOR, polynomial-sigmoid gradient term, k-weighted accumulate.
//   W_k = (z_im*cos - z_re*sin)/16 - sin(4*phi)/786432      (sigma Taylor, z^2=1)
//   g_u0 = -(pi^2/3) * cos(theta) * (1-T0^2) * S
//   g_u1 =  0.4*pi   * (1-T1^2)            * S,   S = sum_k k*W_k
// ---------------------------------------------------------------------------
extern "C" __global__ void __launch_bounds__(256)
refine(const float* __restrict__ th0, const float* __restrict__ r0,
       const float* __restrict__ a_th_raw, const float* __restrict__ a_r_raw,
       const float* __restrict__ l_th_raw, const float* __restrict__ l_r_raw,
       const uint32_t* __restrict__ pr, const uint32_t* __restrict__ pim,
       float* __restrict__ out) {
    const int lane = threadIdx.x & 63;
    const int w    = threadIdx.x >> 6;       // wave id 0..3, owns k in [w*64, w*64+64)
    const int item = blockIdx.x * 64 + lane;

    __shared__ float red[4][64];

    // sign bits for this wave's 64 k's (2 words per component)
    const uint32_t br0 = pr [item * 8 + w * 2 + 0];
    const uint32_t br1 = pr [item * 8 + w * 2 + 1];
    const uint32_t bi0 = pim[item * 8 + w * 2 + 0];
    const uint32_t bi1 = pim[item * 8 + w * 2 + 1];

    // u0 = atanh(theta/60), u1 = atanh(2*(r/2000)-1), with reference clips
    float y = th0[item] * (1.0f / 60.0f);
    y = fminf(fmaxf(y, -1.0f + 1e-6f), 1.0f - 1e-6f);
    float u0 = atanhf(y);
    float sR = r0[item] * (1.0f / 2000.0f);
    sR = fminf(fmaxf(sR, 1e-6f), 1.0f - 1e-6f);
    float u1 = atanhf(2.0f * sR - 1.0f);

    const float w64 = (float)(w * 64);

    for (int t = 0; t < 10; ++t) {
        // per-step params: clip(softplus(raw), lo, hi)
        const float ath = fminf(fmaxf(log1pf(expf(a_th_raw[t])), 1e-6f), 0.2f);
        const float ar  = fminf(fmaxf(log1pf(expf(a_r_raw [t])), 1e-6f), 0.2f);
        const float lth = fminf(fmaxf(log1pf(expf(l_th_raw[t])), 1e-6f), 1.0f);
        const float lr  = fminf(fmaxf(log1pf(expf(l_r_raw [t])), 1e-6f), 1.0f);

        const float T0 = tanhf(u0), T1 = tanhf(u1);
        const float th_rad = (PI_F / 3.0f) * T0;          // 60*T0 deg -> rad
        const float sth = sinf(th_rad), cth = cosf(th_rad);
        const float r   = 1000.0f * (T1 + 1.0f);
        const float crev = 0.5f * sth - 2e-4f * r;        // revolutions per unit k

        // rotation step e^{i*2pi*4*crev}
        const float d4 = fract_(4.0f * crev);
        const float C4 = cos2pi_(d4), S4 = sin2pi_(d4);

        float c[4], s[4], kf[4], acc[4];
        #pragma unroll
        for (int m = 0; m < 4; ++m) {
            const float k0 = w64 + (float)m;
            const float rv = fract_(k0 * crev);
            c[m] = cos2pi_(rv);
            s[m] = sin2pi_(rv);
            kf[m]  = k0;
            acc[m] = 0.0f;
        }

        #pragma unroll
        for (int j = 0; j < 16; ++j) {
            #pragma unroll
            for (int m = 0; m < 4; ++m) {
                const int kl = m + 4 * j;                  // 0..63, compile-time
                const uint32_t wr = (kl < 32) ? br0 : br1;
                const uint32_t wi = (kl < 32) ? bi0 : bi1;
                const int sh = 31 - (kl & 31);
                const uint32_t mre = (wr << sh) & 0x80000000u;
                const uint32_t mim = (wi << sh) & 0x80000000u;
                const float cs = c[m], ss = s[m];
                const float zc = __uint_as_float(__float_as_uint(cs) ^ mim); // z_im*cos
                const float zs = __uint_as_float(__float_as_uint(ss) ^ mre); // z_re*sin
                const float w0 = zc - zs;
                // cubic sigma term: -sin(4phi)/786432 = -s*c*(1-2s^2)/196608
                const float u2 = ss * ss;
                const float t2 = fmaf(-2.0f, u2, 1.0f);
                const float sc = ss * cs;
                const float v  = sc * t2;
                const float W  = fmaf(v, -(1.0f / 196608.0f), w0 * 0.0625f);
                acc[m] = fmaf(kf[m], W, acc[m]);
                kf[m] += 4.0f;
                // rotate phase by 4*crev revolutions
                const float tA = ss * S4;
                const float tB = cs * S4;
                c[m] = fmaf(cs, C4, -tA);
                s[m] = fmaf(ss, C4, tB);
            }
        }
        float S = (acc[0] + acc[1]) + (acc[2] + acc[3]);

        // cross-wave reduce (4 waves hold disjoint k-ranges of the same item)
        red[w][lane] = S;
        __syncthreads();
        S = (red[0][lane] + red[1][lane]) + (red[2][lane] + red[3][lane]);
        __syncthreads();   // protect red[] reuse next iteration

        // gradient of -loglike wrt u, then normalized clipped step
        const float g0 = -(PI_F * PI_F / 3.0f) * cth * (1.0f - T0 * T0) * S;
        const float g1 = 0.4f * PI_F * (1.0f - T1 * T1) * S;
        const float den0 = fmaxf(fabsf(g0), 1e-6f) + lth;
        const float den1 = fmaxf(fabsf(g1), 1e-6f) + lr;
        float st0 = ath * g0 / den0;
        float st1 = ar  * g1 / den1;
        st0 = fminf(fmaxf(st0, -0.1f), 0.1f);
        st1 = fminf(fmaxf(st1, -0.1f), 0.1f);
        u0 -= st0;
        u1 -= st1;
    }

    if (w == 0) {
        const float thT = 60.0f * tanhf(u0);
        const float rT  = 1000.0f * (tanhf(u1) + 1.0f);
        reinterpret_cast<float2*>(out)[item] = make_float2(thT, rT);
    }
}

extern "C" void kernel_launch(void* const* d_in, const int* in_sizes, int n_in,
                              void* d_out, int out_size, void* d_ws, size_t ws_size,
                              hipStream_t stream) {
    const float* zr   = (const float*)d_in[0];
    const float* zi   = (const float*)d_in[1];
    const float* th0  = (const float*)d_in[2];
    const float* r0   = (const float*)d_in[3];
    const float* athr = (const float*)d_in[4];
    const float* arr  = (const float*)d_in[5];
    const float* lthr = (const float*)d_in[6];
    const float* lrr  = (const float*)d_in[7];

    const int B = in_sizes[2];           // 32768
    const int BK = in_sizes[0];          // B*K = 8388608

    uint32_t* pr  = (uint32_t*)d_ws;     // B*8 words = 1 MB
    uint32_t* pim = pr + (size_t)B * 8;  // B*8 words = 1 MB

    pack_signs<<<BK / 256, 256, 0, stream>>>(zr, zi, pr, pim);
    refine<<<B / 64, 256, 0, stream>>>(th0, r0, athr, arr, lthr, lrr, pr, pim,
                                       (float*)d_out);
}